// Round 1
// baseline (433.099 us; speedup 1.0000x reference)
//
#include <hip/hip_runtime.h>

// out[i, j] = x[i, j] * w[j]
// x: ROWS x SIZE fp32, w: SIZE fp32, out: ROWS x SIZE fp32
// ROWS = 16384, SIZE = 4096  -> 64Mi elements, 16Mi float4s.
//
// Memory-bound: 256 MiB in + 256 MiB out. Target ~6.3 TB/s -> ~85 us.

#define SIZE_MASK 4095  // SIZE - 1; SIZE = 4096 is a power of two

__global__ __launch_bounds__(256) void colscale_kernel(
    const float4* __restrict__ x4,
    const float*  __restrict__ w,
    float4* __restrict__ out4,
    long long n4)  // number of float4 elements
{
    long long stride = (long long)gridDim.x * blockDim.x;
    for (long long i = (long long)blockIdx.x * blockDim.x + threadIdx.x;
         i < n4; i += stride) {
        // flat element offset of this float4 = 4*i; column = (4*i) & 4095.
        // SIZE % 4 == 0, so the 4 lanes of this float4 are 4 consecutive
        // columns and map to one aligned float4 of w.
        int col4 = (int)((i << 2) & SIZE_MASK) >> 2;   // float4 index into w
        float4 wv = ((const float4*)w)[col4];          // L1-resident (16 KiB)
        float4 xv = x4[i];
        float4 ov;
        ov.x = xv.x * wv.x;
        ov.y = xv.y * wv.y;
        ov.z = xv.z * wv.z;
        ov.w = xv.w * wv.w;
        out4[i] = ov;
    }
}

extern "C" void kernel_launch(void* const* d_in, const int* in_sizes, int n_in,
                              void* d_out, int out_size, void* d_ws, size_t ws_size,
                              hipStream_t stream) {
    const float* x = (const float*)d_in[0];
    const float* w = (const float*)d_in[1];
    float* out = (float*)d_out;

    long long n  = (long long)out_size;   // 16384 * 4096
    long long n4 = n >> 2;                // float4 count

    const int block = 256;
    // Memory-bound: cap grid at ~2048 blocks (256 CU x 8 blocks/CU),
    // grid-stride the rest.
    long long want = (n4 + block - 1) / block;
    int grid = (int)(want < 2048 ? want : 2048);

    colscale_kernel<<<grid, block, 0, stream>>>(
        (const float4*)x, w, (float4*)out, n4);
}